// Round 1
// baseline (886.496 us; speedup 1.0000x reference)
//
#include <hip/hip_runtime.h>
#include <math.h>

#define B_   4
#define CIN  256
#define CO_  256
#define H_   64
#define W_   64
#define HW   4096
#define K2_  9

// ---------------------------------------------------------------------------
// Kernel A: offset-mask conv (Cin=256 -> 27ch, 3x3, pad 1) fused with the
// coordinate/mask transform. Thread = (b, k, pos). Wave spans one wo-row
// (64 lanes) -> x loads coalesced, weight loads wave-uniform (broadcast).
// Outputs py/px (absolute sampling coords) and sigmoid(mask) to workspace.
// ---------------------------------------------------------------------------
__global__ __launch_bounds__(256) void om_kernel(
    const float* __restrict__ x, const float* __restrict__ w_om,
    const float* __restrict__ b_om,
    float* __restrict__ pybuf, float* __restrict__ pxbuf,
    float* __restrict__ mbuf)
{
    int flat = blockIdx.x * 256 + threadIdx.x;      // B*9*HW = 147456
    int b    = flat / (K2_ * HW);
    int rem  = flat - b * (K2_ * HW);
    int k    = rem >> 12;                            // /4096
    int pos  = rem & (HW - 1);
    int ho   = pos >> 6, wo = pos & 63;

    float o1 = b_om[k], o2 = b_om[k + 9], mm = b_om[k + 18];
    const float* xb = x + (size_t)b * CIN * HW;
    const float* w1 = w_om + (size_t)(k)      * CIN * 9;
    const float* w2 = w_om + (size_t)(k + 9)  * CIN * 9;
    const float* w3 = w_om + (size_t)(k + 18) * CIN * 9;

    for (int ci = 0; ci < CIN; ++ci) {
        const float* xp = xb + ci * HW;
        #pragma unroll
        for (int r = 0; r < 3; ++r) {
            int y = ho - 1 + r;
            if (y < 0 || y >= H_) continue;          // wave-uniform branch
            const float* row = xp + y * W_;
            #pragma unroll
            for (int c = 0; c < 3; ++c) {
                int xx = wo - 1 + c;
                float v = (xx >= 0 && xx < W_) ? row[xx] : 0.0f;
                int wi = ci * 9 + r * 3 + c;
                o1 = fmaf(v, w1[wi], o1);
                o2 = fmaf(v, w2[wi], o2);
                mm = fmaf(v, w3[wi], mm);
            }
        }
    }
    int khs = k / 3, kws = k - khs * 3;
    pybuf[flat] = (float)(ho - 1 + khs) + o1;
    pxbuf[flat] = (float)(wo - 1 + kws) + o2;
    mbuf[flat]  = 1.0f / (1.0f + expf(-mm));
}

// ---------------------------------------------------------------------------
// Kernel W: transpose w_dcn[co][ci][k] -> w_t[k][ci][co] (coalesced writes)
// ---------------------------------------------------------------------------
__global__ __launch_bounds__(256) void wt_kernel(
    const float* __restrict__ w_dcn, float* __restrict__ w_t)
{
    int i  = blockIdx.x * 256 + threadIdx.x;        // 9*256*256 = 589824
    int co = i & 255;
    int t  = i >> 8;
    int ci = t & 255;
    int k  = t >> 8;
    w_t[i] = w_dcn[((size_t)co * 256 + ci) * 9 + k];
}

// ---------------------------------------------------------------------------
// Kernel B: fused bilinear-sample + masked im2col + GEMM + bias + ReLU.
// Block = (b, ho): 256 co x 64 pos output tile, 256 threads.
// Thread tile: 8 co x 8 pos (ct = tid&31 -> co0=ct*8 ; pt = tid>>5 -> p0=pt*8)
// K-loop: 9 kernel taps x 16-ci chunks; per chunk stage sampled*mask [16][64]
// and w_t chunk [16][256] in LDS, then 8x8 f32 outer-product FMAs.
// ---------------------------------------------------------------------------
__global__ __launch_bounds__(256) void dcn_main(
    const float* __restrict__ x, const float* __restrict__ w_t,
    const float* __restrict__ b_dcn,
    const float* __restrict__ pybuf, const float* __restrict__ pxbuf,
    const float* __restrict__ mbuf, float* __restrict__ out)
{
    int b    = blockIdx.x >> 6;
    int ho   = blockIdx.x & 63;
    int pos0 = ho * 64;
    int tid  = threadIdx.x;
    int ct   = tid & 31, pt = tid >> 5;
    int co0  = ct * 8;
    int p0   = pt * 8;

    __shared__ __align__(16) float s_w[16][256];     // w_t chunk [cil][co]
    __shared__ __align__(16) float s_samp[16][64];   // sampled*mask [cil][p]
    __shared__ float s_dy[64], s_dx[64], s_m[64];
    __shared__ int   s_y0[64], s_x0[64];

    float acc[8][8];
    #pragma unroll
    for (int i = 0; i < 8; ++i)
        #pragma unroll
        for (int j = 0; j < 8; ++j) acc[i][j] = 0.0f;

    const float* xb = x + (size_t)b * CIN * HW;

    for (int k = 0; k < 9; ++k) {
        __syncthreads();
        if (tid < 64) {
            int idx = (b * K2_ + k) * HW + pos0 + tid;
            float py = pybuf[idx], px = pxbuf[idx];
            float fy = floorf(py), fx = floorf(px);
            s_y0[tid] = (int)fy;  s_x0[tid] = (int)fx;
            s_dy[tid] = py - fy;  s_dx[tid] = px - fx;
            s_m[tid]  = mbuf[idx];
        }
        __syncthreads();

        for (int ci0 = 0; ci0 < CIN; ci0 += 16) {
            // ---- stage w chunk: 16x256 floats, fully coalesced float4 ----
            const float4* wsrc = (const float4*)(w_t + ((size_t)k * 256 + ci0) * 256);
            float4* wdst = (float4*)&s_w[0][0];
            #pragma unroll
            for (int j = 0; j < 4; ++j)
                wdst[tid + 256 * j] = wsrc[tid + 256 * j];

            // ---- stage sampled*mask: 16 ci x 64 pos, 4 tasks/thread ----
            #pragma unroll
            for (int j = 0; j < 4; ++j) {
                int task = tid + 256 * j;            // 0..1023
                int p    = task & 63;
                int cil  = task >> 6;
                int y0 = s_y0[p], x0 = s_x0[p];
                float dy = s_dy[p], dx = s_dx[p];
                const float* xp = xb + (ci0 + cil) * HW;
                bool yv0 = (y0 >= 0)     & (y0 < H_);
                bool yv1 = (y0 >= -1)    & (y0 < H_ - 1);
                bool xv0 = (x0 >= 0)     & (x0 < W_);
                bool xv1 = (x0 >= -1)    & (x0 < W_ - 1);
                float v00 = (yv0 & xv0) ? xp[y0 * W_ + x0]           : 0.0f;
                float v01 = (yv0 & xv1) ? xp[y0 * W_ + x0 + 1]       : 0.0f;
                float v10 = (yv1 & xv0) ? xp[(y0 + 1) * W_ + x0]     : 0.0f;
                float v11 = (yv1 & xv1) ? xp[(y0 + 1) * W_ + x0 + 1] : 0.0f;
                float v = v00 * (1.0f - dy) * (1.0f - dx)
                        + v01 * (1.0f - dy) * dx
                        + v10 * dy * (1.0f - dx)
                        + v11 * dy * dx;
                s_samp[cil][p] = v * s_m[p];
            }
            __syncthreads();

            // ---- 8x8 register-tile outer product over 16 ci ----
            #pragma unroll
            for (int cil = 0; cil < 16; ++cil) {
                float4 wa = *(const float4*)&s_w[cil][co0];
                float4 wb = *(const float4*)&s_w[cil][co0 + 4];
                float4 sa = *(const float4*)&s_samp[cil][p0];
                float4 sb = *(const float4*)&s_samp[cil][p0 + 4];
                float wv[8] = {wa.x, wa.y, wa.z, wa.w, wb.x, wb.y, wb.z, wb.w};
                float sv[8] = {sa.x, sa.y, sa.z, sa.w, sb.x, sb.y, sb.z, sb.w};
                #pragma unroll
                for (int i = 0; i < 8; ++i)
                    #pragma unroll
                    for (int j = 0; j < 8; ++j)
                        acc[i][j] = fmaf(wv[i], sv[j], acc[i][j]);
            }
            __syncthreads();
        }
    }

    // ---- epilogue: bias + ReLU, 64B-contiguous stores per co row ----
    #pragma unroll
    for (int i = 0; i < 8; ++i) {
        float bias = b_dcn[co0 + i];
        float* op = out + ((size_t)(b * CO_ + co0 + i)) * HW + pos0 + p0;
        float4 r0, r1;
        r0.x = fmaxf(acc[i][0] + bias, 0.0f);
        r0.y = fmaxf(acc[i][1] + bias, 0.0f);
        r0.z = fmaxf(acc[i][2] + bias, 0.0f);
        r0.w = fmaxf(acc[i][3] + bias, 0.0f);
        r1.x = fmaxf(acc[i][4] + bias, 0.0f);
        r1.y = fmaxf(acc[i][5] + bias, 0.0f);
        r1.z = fmaxf(acc[i][6] + bias, 0.0f);
        r1.w = fmaxf(acc[i][7] + bias, 0.0f);
        *(float4*)op = r0;
        *(float4*)(op + 4) = r1;
    }
}

// ---------------------------------------------------------------------------
extern "C" void kernel_launch(void* const* d_in, const int* in_sizes, int n_in,
                              void* d_out, int out_size, void* d_ws, size_t ws_size,
                              hipStream_t stream) {
    const float* x     = (const float*)d_in[0];
    const float* w_om  = (const float*)d_in[1];
    const float* b_om  = (const float*)d_in[2];
    const float* w_dcn = (const float*)d_in[3];
    const float* b_dcn = (const float*)d_in[4];
    float* out = (float*)d_out;

    float* ws  = (float*)d_ws;
    float* py  = ws;                        // B*9*HW = 147456 floats
    float* px  = ws + 147456;
    float* m   = ws + 294912;
    float* w_t = ws + 442368;               // 9*256*256 = 589824 floats

    om_kernel<<<576, 256, 0, stream>>>(x, w_om, b_om, py, px, m);
    wt_kernel<<<2304, 256, 0, stream>>>(w_dcn, w_t);
    dcn_main<<<256, 256, 0, stream>>>(x, w_t, b_dcn, py, px, m, out);
}

// Round 2
// 498.371 us; speedup vs baseline: 1.7788x; 1.7788x over previous
//
#include <hip/hip_runtime.h>
#include <math.h>

typedef _Float16 f16x8 __attribute__((ext_vector_type(8)));
typedef float f32x4 __attribute__((ext_vector_type(4)));
typedef unsigned short ushort_t;

#define HW   4096
#define CIN  256
#define CO_  256

__device__ __forceinline__ ushort_t f2h(float v) {
    union { _Float16 h; ushort_t u; } cv;
    cv.h = (_Float16)v;
    return cv.u;
}

// ---------------------------------------------------------------------------
// prep_w: convert weights to f16 in MFMA-chunk-ready layouts.
//   w16  [9][8][256co][32kk]  = w_dcn[co][c8*32+kk][k]
//   wom16[9][8][32m ][32kk]   = w_om [m ][c8*32+kk][k]   (m>=27 -> 0)
// ---------------------------------------------------------------------------
__global__ __launch_bounds__(256) void prep_w(
    const float* __restrict__ w_dcn, const float* __restrict__ w_om,
    ushort_t* __restrict__ w16, ushort_t* __restrict__ wom16)
{
    int flat = blockIdx.x * 256 + threadIdx.x;   // 589824 + 73728
    if (flat < 589824) {
        int kk = flat & 31, co = (flat >> 5) & 255, c8 = (flat >> 13) & 7, k = flat >> 16;
        w16[flat] = f2h(w_dcn[(size_t)(co * 256 + c8 * 32 + kk) * 9 + k]);
    } else {
        int o = flat - 589824;
        int kk = o & 31, m = (o >> 5) & 31, c8 = (o >> 10) & 7, k = o >> 13;
        float v = (m < 27) ? w_om[(size_t)(m * 256 + c8 * 32 + kk) * 9 + k] : 0.0f;
        wom16[o] = f2h(v);
    }
}

// ---------------------------------------------------------------------------
// om_mfma: offset-mask conv as MFMA GEMM. M=32(pad27), K=(tap,ci), N=pos.
// Block = 1 wave (64 thr): tile 32m x 64pos (one ho row), K-split by 3 taps.
// Writes f32 partials [b][part3][32][4096].
// ---------------------------------------------------------------------------
__global__ __launch_bounds__(64) void om_mfma(
    const float* __restrict__ x, const ushort_t* __restrict__ wom16,
    float* __restrict__ part)
{
    int bid = blockIdx.x;                 // (b*64 + ho)*3 + pr
    int pr = bid % 3;
    int t2 = bid / 3;
    int ho = t2 & 63;
    int b  = t2 >> 6;
    int l  = threadIdx.x;
    int kb = l >> 4, c16 = l & 15;

    __shared__ __align__(16) ushort_t s_a[32 * 32];
    __shared__ __align__(16) ushort_t s_s[64 * 32];

    f32x4 zv = {0.f, 0.f, 0.f, 0.f};
    f32x4 acc[2][4];
    #pragma unroll
    for (int i = 0; i < 2; ++i)
        #pragma unroll
        for (int j = 0; j < 4; ++j) acc[i][j] = zv;

    f16x8 hz;
    #pragma unroll
    for (int j = 0; j < 8; ++j) hz[j] = (_Float16)0.0f;

    const float* xb = x + (size_t)b * CIN * HW;

    for (int tt = 0; tt < 3; ++tt) {
        int k = pr * 3 + tt;
        int kh = k / 3, kw = k - kh * 3;
        int y  = ho - 1 + kh;
        bool yv = (y >= 0) && (y < 64);
        int xc  = l - 1 + kw;             // pos = lane
        bool xv = (xc >= 0) && (xc < 64);
        for (int c8 = 0; c8 < 8; ++c8) {
            // A chunk: 2 KB contiguous, 2 float4/thread
            const float4* asrc = (const float4*)(wom16 + (size_t)(k * 8 + c8) * 1024);
            float4 a0 = asrc[l * 2], a1 = asrc[l * 2 + 1];
            // S: 32 ci values at (y, xc) for this lane's pos
            f16x8 hv[4];
            if (yv) {
                const float* bp = xb + (size_t)(c8 * 32) * HW + y * 64 + xc;
                #pragma unroll
                for (int q = 0; q < 4; ++q)
                    #pragma unroll
                    for (int j = 0; j < 8; ++j) {
                        float v = xv ? bp[(size_t)(q * 8 + j) * HW] : 0.0f;
                        hv[q][j] = (_Float16)v;
                    }
            } else {
                #pragma unroll
                for (int q = 0; q < 4; ++q) hv[q] = hz;
            }
            __syncthreads();
            {
                int v0 = l * 2, v1 = l * 2 + 1;
                int m0 = v0 >> 2, q0 = v0 & 3, m1 = v1 >> 2, q1 = v1 & 3;
                *(float4*)((char*)s_a + ((m0 * 64 + q0 * 16) ^ ((m0 & 7) << 4))) = a0;
                *(float4*)((char*)s_a + ((m1 * 64 + q1 * 16) ^ ((m1 & 7) << 4))) = a1;
                #pragma unroll
                for (int q = 0; q < 4; ++q)
                    *(f16x8*)((char*)s_s + ((l * 64 + q * 16) ^ ((l & 7) << 4))) = hv[q];
            }
            __syncthreads();
            f16x8 af[2], bf[4];
            #pragma unroll
            for (int i = 0; i < 2; ++i) {
                int row = i * 16 + c16;
                af[i] = *(const f16x8*)((const char*)s_a + ((row * 64 + kb * 16) ^ ((row & 7) << 4)));
            }
            #pragma unroll
            for (int j = 0; j < 4; ++j) {
                int row = j * 16 + c16;
                bf[j] = *(const f16x8*)((const char*)s_s + ((row * 64 + kb * 16) ^ ((row & 7) << 4)));
            }
            #pragma unroll
            for (int i = 0; i < 2; ++i)
                #pragma unroll
                for (int j = 0; j < 4; ++j)
                    acc[i][j] = __builtin_amdgcn_mfma_f32_16x16x32_f16(af[i], bf[j], acc[i][j], 0, 0, 0);
        }
    }
    int pos0 = ho * 64;
    #pragma unroll
    for (int i = 0; i < 2; ++i)
        #pragma unroll
        for (int j = 0; j < 4; ++j)
            #pragma unroll
            for (int r = 0; r < 4; ++r) {
                int m = i * 16 + kb * 4 + r;
                int pos = j * 16 + c16;
                part[(size_t)((b * 3 + pr) * 32 + m) * HW + pos0 + pos] = acc[i][j][r];
            }
}

// ---------------------------------------------------------------------------
// om_reduce: sum 3 K-partials + bias, transform to py/px/sigmoid(mask).
// ---------------------------------------------------------------------------
__global__ __launch_bounds__(256) void om_reduce(
    const float* __restrict__ part, const float* __restrict__ b_om,
    float* __restrict__ py, float* __restrict__ px, float* __restrict__ msk)
{
    int flat = blockIdx.x * 256 + threadIdx.x;   // 4*27*4096
    int pos = flat & 4095;
    int t = flat >> 12;
    int ch = t % 27;
    int b = t / 27;
    float val = b_om[ch];
    #pragma unroll
    for (int pr = 0; pr < 3; ++pr)
        val += part[(size_t)((b * 3 + pr) * 32 + ch) * HW + pos];
    int ho = pos >> 6, wo = pos & 63;
    if (ch < 9) {
        int kh = ch / 3;
        py[(size_t)(b * 9 + ch) * HW + pos] = (float)(ho - 1 + kh) + val;
    } else if (ch < 18) {
        int k = ch - 9, kw = k % 3;
        px[(size_t)(b * 9 + k) * HW + pos] = (float)(wo - 1 + kw) + val;
    } else {
        int k = ch - 18;
        msk[(size_t)(b * 9 + k) * HW + pos] = 1.0f / (1.0f + expf(-val));
    }
}

// ---------------------------------------------------------------------------
// dcn_main: fused bilinear-sample + masked im2col + MFMA GEMM + bias + ReLU.
// Block = 128co x 64pos (one ho row), 4 waves; wave = 32co x 64pos.
// Grid = 4b * 64ho * 2cohalf = 512 -> 2 blocks/CU.
// K loop: 9 taps x 8 ci-chunks of 32. LDS XOR-swizzled (st-style) for
// conflict-free ds_read_b128 fragments.
// ---------------------------------------------------------------------------
__global__ __launch_bounds__(256) void dcn_main(
    const float* __restrict__ x, const ushort_t* __restrict__ w16,
    const float* __restrict__ b_dcn,
    const float* __restrict__ py, const float* __restrict__ px,
    const float* __restrict__ msk, float* __restrict__ out)
{
    int bid = blockIdx.x;
    int half = bid & 1;
    int ho = (bid >> 1) & 63;
    int b = bid >> 7;
    int co0 = half * 128;
    int pos0 = ho * 64;
    int tid = threadIdx.x;
    int w = tid >> 6;          // wave id, also ci-group for staging
    int l = tid & 63;
    int kb = l >> 4, c16 = l & 15;
    int p = l;                 // staging pos

    __shared__ __align__(16) ushort_t s_w[128 * 32];   // 8 KB
    __shared__ __align__(16) ushort_t s_s[64 * 32];    // 4 KB

    f32x4 zv = {0.f, 0.f, 0.f, 0.f};
    f32x4 acc[2][4];
    #pragma unroll
    for (int i = 0; i < 2; ++i)
        #pragma unroll
        for (int j = 0; j < 4; ++j) acc[i][j] = zv;

    const float* xb = x + (size_t)b * CIN * HW;

    for (int k = 0; k < 9; ++k) {
        // per-tap bilinear data for this thread's pos (recomputed per cig; cheap)
        size_t gidx = (size_t)(b * 9 + k) * HW + pos0 + p;
        float fy = py[gidx], fx = px[gidx], mv = msk[gidx];
        float y0f = floorf(fy), x0f = floorf(fx);
        int y0 = (int)y0f, x0 = (int)x0f;
        float dy = fy - y0f, dx = fx - x0f;
        bool vy0 = (y0 >= 0) & (y0 < 64);
        bool vy1 = (y0 >= -1) & (y0 < 63);
        bool vx0 = (x0 >= 0) & (x0 < 64);
        bool vx1 = (x0 >= -1) & (x0 < 63);
        int y0c = min(max(y0, 0), 63), y1c = min(max(y0 + 1, 0), 63);
        int x0c = min(max(x0, 0), 63), x1c = min(max(x0 + 1, 0), 63);
        int i00 = y0c * 64 + x0c, i01 = y0c * 64 + x1c;
        int i10 = y1c * 64 + x0c, i11 = y1c * 64 + x1c;
        float w00 = (vy0 && vx0) ? (1.f - dy) * (1.f - dx) * mv : 0.f;
        float w01 = (vy0 && vx1) ? (1.f - dy) * dx * mv : 0.f;
        float w10 = (vy1 && vx0) ? dy * (1.f - dx) * mv : 0.f;
        float w11 = (vy1 && vx1) ? dy * dx * mv : 0.f;

        for (int c8 = 0; c8 < 8; ++c8) {
            // issue global loads early (overlap with previous chunk's MFMA)
            const float4* wsrc = (const float4*)(w16 + (size_t)((k * 8 + c8) * 256 + co0) * 32);
            float4 wa = wsrc[tid], wb = wsrc[tid + 256];
            int cibase = c8 * 32 + w * 8;
            f16x8 hv;
            #pragma unroll
            for (int j = 0; j < 8; ++j) {
                const float* bp = xb + ((size_t)(cibase + j) << 12);
                float v = bp[i00] * w00 + bp[i01] * w01 + bp[i10] * w10 + bp[i11] * w11;
                hv[j] = (_Float16)v;
            }
            __syncthreads();   // previous chunk's frag reads complete
            {
                int v0 = tid, v1 = tid + 256;
                int c0 = v0 >> 2, q0 = v0 & 3, c1 = v1 >> 2, q1 = v1 & 3;
                *(float4*)((char*)s_w + ((c0 * 64 + q0 * 16) ^ ((c0 & 7) << 4))) = wa;
                *(float4*)((char*)s_w + ((c1 * 64 + q1 * 16) ^ ((c1 & 7) << 4))) = wb;
                *(f16x8*)((char*)s_s + ((p * 64 + w * 16) ^ ((p & 7) << 4))) = hv;
            }
            __syncthreads();
            f16x8 af[2], bf[4];
            #pragma unroll
            for (int i = 0; i < 2; ++i) {
                int row = w * 32 + i * 16 + c16;
                af[i] = *(const f16x8*)((const char*)s_w + ((row * 64 + kb * 16) ^ ((row & 7) << 4)));
            }
            #pragma unroll
            for (int j = 0; j < 4; ++j) {
                int row = j * 16 + c16;
                bf[j] = *(const f16x8*)((const char*)s_s + ((row * 64 + kb * 16) ^ ((row & 7) << 4)));
            }
            #pragma unroll
            for (int i = 0; i < 2; ++i)
                #pragma unroll
                for (int j = 0; j < 4; ++j)
                    acc[i][j] = __builtin_amdgcn_mfma_f32_16x16x32_f16(af[i], bf[j], acc[i][j], 0, 0, 0);
        }
    }

    // epilogue: bias + ReLU; lanes c16 give 64B-contiguous segments
    #pragma unroll
    for (int i = 0; i < 2; ++i) {
        #pragma unroll
        for (int r = 0; r < 4; ++r) {
            int co = co0 + w * 32 + i * 16 + kb * 4 + r;
            float bias = b_dcn[co];
            float* orow = out + (size_t)(b * 256 + co) * HW + pos0;
            #pragma unroll
            for (int j = 0; j < 4; ++j) {
                float v2 = acc[i][j][r] + bias;
                orow[j * 16 + c16] = fmaxf(v2, 0.f);
            }
        }
    }
}

// ---------------------------------------------------------------------------
extern "C" void kernel_launch(void* const* d_in, const int* in_sizes, int n_in,
                              void* d_out, int out_size, void* d_ws, size_t ws_size,
                              hipStream_t stream) {
    const float* x     = (const float*)d_in[0];
    const float* w_om  = (const float*)d_in[1];
    const float* b_om  = (const float*)d_in[2];
    const float* w_dcn = (const float*)d_in[3];
    const float* b_dcn = (const float*)d_in[4];
    float* out = (float*)d_out;

    float* ws   = (float*)d_ws;
    float* py   = ws;                          // 147456
    float* px   = ws + 147456;
    float* msk  = ws + 294912;
    float* part = ws + 442368;                 // [4][3][32][4096] = 1572864
    ushort_t* w16   = (ushort_t*)(ws + 2015232);   // 589824 f16
    ushort_t* wom16 = w16 + 589824;                // 73728 f16

    prep_w   <<<2592, 256, 0, stream>>>(w_dcn, w_om, w16, wom16);
    om_mfma  <<<768,   64, 0, stream>>>(x, wom16, part);
    om_reduce<<<1728, 256, 0, stream>>>(part, b_om, py, px, msk);
    dcn_main <<<512,  256, 0, stream>>>(x, w16, b_dcn, py, px, msk, out);
}

// Round 3
// 181.169 us; speedup vs baseline: 4.8932x; 2.7509x over previous
//
#include <hip/hip_runtime.h>
#include <math.h>

typedef _Float16 f16x8 __attribute__((ext_vector_type(8)));
typedef float f32x4 __attribute__((ext_vector_type(4)));
typedef unsigned short ushort_t;

#define HW 4096

__device__ __forceinline__ ushort_t f2h_u(float v) {
    union { _Float16 h; ushort_t u; } cv; cv.h = (_Float16)v; return cv.u;
}

#define MFMA16 __builtin_amdgcn_mfma_f32_16x16x32_f16

// ---------------------------------------------------------------------------
// prep_w: f16 weight layouts.
//   w16  [9][8][256co][32kk] = w_dcn[co][c8*32+kk][k]
//   wom16[9][8][32m ][32kk]  = w_om [m ][c8*32+kk][k]  (m>=27 -> 0)
// ---------------------------------------------------------------------------
__global__ __launch_bounds__(256) void prep_w(
    const float* __restrict__ w_dcn, const float* __restrict__ w_om,
    ushort_t* __restrict__ w16, ushort_t* __restrict__ wom16)
{
    int flat = blockIdx.x * 256 + threadIdx.x;   // 589824 + 73728
    if (flat < 589824) {
        int kk = flat & 31, co = (flat >> 5) & 255, c8 = (flat >> 13) & 7, k = flat >> 16;
        w16[flat] = f2h_u(w_dcn[(size_t)(co * 256 + c8 * 32 + kk) * 9 + k]);
    } else {
        int o = flat - 589824;
        int kk = o & 31, m = (o >> 5) & 31, c8 = (o >> 10) & 7, k = o >> 13;
        float v = (m < 27) ? w_om[(size_t)(m * 256 + c8 * 32 + kk) * 9 + k] : 0.0f;
        wom16[o] = f2h_u(v);
    }
}

// ---------------------------------------------------------------------------
// xpose: x f32 [b][ci][pos] -> xT f16 [b][pos][ci]. Lanes = consecutive pos
// so the 8 strided ci reads are each 256B-coalesced across the wave.
// ---------------------------------------------------------------------------
__global__ __launch_bounds__(256) void xpose(
    const float* __restrict__ x, ushort_t* __restrict__ xT)
{
    int flat = blockIdx.x * 256 + threadIdx.x;   // 4b * 32gq * 4096pos
    int pos = flat & 4095;
    int gq  = (flat >> 12) & 31;
    int b   = flat >> 17;
    const float* xb = x + ((size_t)(b * 256 + gq * 8)) * HW + pos;
    f16x8 hv;
    #pragma unroll
    for (int j = 0; j < 8; ++j) hv[j] = (_Float16)xb[(size_t)j << 12];
    *(f16x8*)(xT + (((size_t)b * HW + pos) * 256) + gq * 8) = hv;
}

// ---------------------------------------------------------------------------
// om_gemm: offset-mask conv as barrier-free MFMA GEMM. M=32(pad27), N=pos,
// K=(tap,ci). Wave = 32m x 64pos (one ho row); K-split x4 by ci quarters.
// B-frags read directly from xT with integer tap shifts (zeroed at borders).
// ---------------------------------------------------------------------------
__global__ __launch_bounds__(256) void om_gemm(
    const ushort_t* __restrict__ xT, const ushort_t* __restrict__ wom16,
    float* __restrict__ part)
{
    int wid = blockIdx.x * 4 + (threadIdx.x >> 6);  // 1024 waves
    int s  = wid & 3;
    int ho = (wid >> 2) & 63;
    int b  = wid >> 8;
    int l  = threadIdx.x & 63;
    int kb = l >> 4, c16 = l & 15;

    f32x4 zv = {0.f, 0.f, 0.f, 0.f};
    f32x4 acc[2][4];
    #pragma unroll
    for (int i = 0; i < 2; ++i)
        #pragma unroll
        for (int j = 0; j < 4; ++j) acc[i][j] = zv;
    f16x8 hz;
    #pragma unroll
    for (int j = 0; j < 8; ++j) hz[j] = (_Float16)0.0f;

    const ushort_t* xTb = xT + (size_t)b * HW * 256;

    for (int k9 = 0; k9 < 9; ++k9) {
        int kh = k9 / 3, kw = k9 - kh * 3;
        int y = ho - 1 + kh;
        bool yv = (y >= 0) & (y < 64);
        int yc = min(max(y, 0), 63);
        #pragma unroll
        for (int cc = 0; cc < 2; ++cc) {
            int c8 = s * 2 + cc;
            const ushort_t* wp = wom16 + ((size_t)((k9 * 8 + c8) * 32 + c16)) * 32 + kb * 8;
            f16x8 a0 = *(const f16x8*)wp;
            f16x8 a1 = *(const f16x8*)(wp + 512);
            f16x8 bf[4];
            #pragma unroll
            for (int jt = 0; jt < 4; ++jt) {
                int wo = jt * 16 + c16;
                int wox = wo + kw - 1;
                bool v = yv & (wox >= 0) & (wox < 64);
                int woc = min(max(wox, 0), 63);
                const ushort_t* sp = xTb + ((size_t)(yc * 64 + woc)) * 256 + c8 * 32 + kb * 8;
                f16x8 bv = *(const f16x8*)sp;
                bf[jt] = v ? bv : hz;
            }
            #pragma unroll
            for (int jt = 0; jt < 4; ++jt) {
                acc[0][jt] = MFMA16(a0, bf[jt], acc[0][jt], 0, 0, 0);
                acc[1][jt] = MFMA16(a1, bf[jt], acc[1][jt], 0, 0, 0);
            }
        }
    }
    int pos0 = ho * 64;
    #pragma unroll
    for (int i = 0; i < 2; ++i)
        #pragma unroll
        for (int jt = 0; jt < 4; ++jt)
            #pragma unroll
            for (int r = 0; r < 4; ++r) {
                int m = i * 16 + kb * 4 + r;
                part[((size_t)(b * 4 + s) * 32 + m) * HW + pos0 + jt * 16 + c16] = acc[i][jt][r];
            }
}

// ---------------------------------------------------------------------------
// om_reduce: sum 4 K-partials + bias -> py/px/sigmoid(mask).
// ---------------------------------------------------------------------------
__global__ __launch_bounds__(256) void om_reduce(
    const float* __restrict__ part, const float* __restrict__ b_om,
    float* __restrict__ py, float* __restrict__ px, float* __restrict__ msk)
{
    int flat = blockIdx.x * 256 + threadIdx.x;   // 4*27*4096
    int pos = flat & 4095;
    int t = flat >> 12;
    int ch = t % 27;
    int b = t / 27;
    float val = b_om[ch];
    #pragma unroll
    for (int pr = 0; pr < 4; ++pr)
        val += part[((size_t)(b * 4 + pr) * 32 + ch) * HW + pos];
    int ho = pos >> 6, wo = pos & 63;
    if (ch < 9) {
        int kh = ch / 3;
        py[(size_t)(b * 9 + ch) * HW + pos] = (float)(ho - 1 + kh) + val;
    } else if (ch < 18) {
        int k = ch - 9, kw = k % 3;
        px[(size_t)(b * 9 + k) * HW + pos] = (float)(wo - 1 + kw) + val;
    } else {
        int k = ch - 18;
        msk[(size_t)(b * 9 + k) * HW + pos] = 1.0f / (1.0f + expf(-val));
    }
}

// ---------------------------------------------------------------------------
// dcn_sample: masked bilinear im2col -> S f16, layout [(SB*32+g)][pos][8ci]
// (SB = brel*9+k, g = ci>>3), so a GEMM B-fragment is one 16B load.
// Thread = (brel,k,pos); writes are 1KB-contiguous per wave.
// ---------------------------------------------------------------------------
__global__ __launch_bounds__(256) void dcn_sample(
    const float* __restrict__ x, const float* __restrict__ py,
    const float* __restrict__ px, const float* __restrict__ msk,
    ushort_t* __restrict__ S, int b0)
{
    int flat = blockIdx.x * 256 + threadIdx.x;   // nb*9*4096
    int pos = flat & 4095;
    int t = flat >> 12;                           // brel*9 + k
    int brel = t / 9;
    int k = t - brel * 9;
    int b = b0 + brel;
    size_t gidx = (size_t)(b * 9 + k) * HW + pos;
    float fy = py[gidx], fx = px[gidx], mv = msk[gidx];
    float y0f = floorf(fy), x0f = floorf(fx);
    int y0 = (int)y0f, x0 = (int)x0f;
    float dy = fy - y0f, dx = fx - x0f;
    bool vy0 = (y0 >= 0) & (y0 < 64);
    bool vy1 = (y0 >= -1) & (y0 < 63);
    bool vx0 = (x0 >= 0) & (x0 < 64);
    bool vx1 = (x0 >= -1) & (x0 < 63);
    int y0c = min(max(y0, 0), 63), y1c = min(max(y0 + 1, 0), 63);
    int x0c = min(max(x0, 0), 63), x1c = min(max(x0 + 1, 0), 63);
    int i00 = y0c * 64 + x0c, i01 = y0c * 64 + x1c;
    int i10 = y1c * 64 + x0c, i11 = y1c * 64 + x1c;
    float w00 = (vy0 && vx0) ? (1.f - dy) * (1.f - dx) * mv : 0.f;
    float w01 = (vy0 && vx1) ? (1.f - dy) * dx * mv : 0.f;
    float w10 = (vy1 && vx0) ? dy * (1.f - dx) * mv : 0.f;
    float w11 = (vy1 && vx1) ? dy * dx * mv : 0.f;

    const float* xb = x + (size_t)b * 256 * HW;
    ushort_t* Sp = S + ((size_t)t * 32 * HW + pos) * 8;
    for (int g = 0; g < 32; ++g) {
        f16x8 hv;
        #pragma unroll
        for (int j = 0; j < 8; ++j) {
            const float* bp = xb + ((size_t)(g * 8 + j) << 12);
            float v = bp[i00] * w00 + bp[i01] * w01 + bp[i10] * w10 + bp[i11] * w11;
            hv[j] = (_Float16)v;
        }
        *(f16x8*)(Sp + (size_t)g * (HW * 8)) = hv;
    }
}

// ---------------------------------------------------------------------------
// dcn_gemm: barrier-free, LDS-free MFMA GEMM. Block = 4 waves sharing one
// 64-pos tile (L1 reuse of B-frags); wave = 32co x 64pos. 2-deep manual
// pipeline: loads of chunk n+1 issued before MFMAs of chunk n.
// ---------------------------------------------------------------------------
__device__ __forceinline__ void ld_chunk(
    const ushort_t* __restrict__ w16, const ushort_t* __restrict__ S,
    int it, int co_a, int c16, int kb, size_t sb32, int posw,
    f16x8& a0, f16x8& a1, f16x8& b0, f16x8& b1, f16x8& b2, f16x8& b3)
{
    int k9 = it >> 3, c8 = it & 7;
    const ushort_t* wp = w16 + ((size_t)((k9 * 8 + c8) * 256 + co_a)) * 32 + kb * 8;
    a0 = *(const f16x8*)wp;
    a1 = *(const f16x8*)(wp + 512);
    const ushort_t* sp = S + ((sb32 + (size_t)(k9 * 32 + c8 * 4 + kb)) * HW + posw + c16) * 8;
    b0 = *(const f16x8*)sp;
    b1 = *(const f16x8*)(sp + 128);
    b2 = *(const f16x8*)(sp + 256);
    b3 = *(const f16x8*)(sp + 384);
}

__global__ __launch_bounds__(256) void dcn_gemm(
    const ushort_t* __restrict__ w16, const ushort_t* __restrict__ S,
    const float* __restrict__ b_dcn, float* __restrict__ out, int b0)
{
    int bid = blockIdx.x;
    int chalf = bid & 1;
    int pt = bid >> 1;
    int brel = pt >> 6;
    int b = b0 + brel;
    int posw = (pt & 63) * 64;
    int tid = threadIdx.x;
    int w = tid >> 6, l = tid & 63;
    int kb = l >> 4, c16 = l & 15;
    int co0w = chalf * 128 + w * 32;
    int co_a = co0w + c16;
    size_t sb32 = (size_t)brel * 288;

    f32x4 zv = {0.f, 0.f, 0.f, 0.f};
    f32x4 acc[2][4];
    #pragma unroll
    for (int i = 0; i < 2; ++i)
        #pragma unroll
        for (int j = 0; j < 4; ++j) acc[i][j] = zv;

    f16x8 a0A, a1A, b0A, b1A, b2A, b3A;
    f16x8 a0B, a1B, b0B, b1B, b2B, b3B;

#define MMQ(A0, A1, B0, B1, B2, B3)                          \
    do {                                                      \
        acc[0][0] = MFMA16(A0, B0, acc[0][0], 0, 0, 0);       \
        acc[1][0] = MFMA16(A1, B0, acc[1][0], 0, 0, 0);       \
        acc[0][1] = MFMA16(A0, B1, acc[0][1], 0, 0, 0);       \
        acc[1][1] = MFMA16(A1, B1, acc[1][1], 0, 0, 0);       \
        acc[0][2] = MFMA16(A0, B2, acc[0][2], 0, 0, 0);       \
        acc[1][2] = MFMA16(A1, B2, acc[1][2], 0, 0, 0);       \
        acc[0][3] = MFMA16(A0, B3, acc[0][3], 0, 0, 0);       \
        acc[1][3] = MFMA16(A1, B3, acc[1][3], 0, 0, 0);       \
    } while (0)

    ld_chunk(w16, S, 0, co_a, c16, kb, sb32, posw, a0A, a1A, b0A, b1A, b2A, b3A);
    for (int it = 0; it < 70; it += 2) {
        ld_chunk(w16, S, it + 1, co_a, c16, kb, sb32, posw, a0B, a1B, b0B, b1B, b2B, b3B);
        MMQ(a0A, a1A, b0A, b1A, b2A, b3A);
        ld_chunk(w16, S, it + 2, co_a, c16, kb, sb32, posw, a0A, a1A, b0A, b1A, b2A, b3A);
        MMQ(a0B, a1B, b0B, b1B, b2B, b3B);
    }
    ld_chunk(w16, S, 71, co_a, c16, kb, sb32, posw, a0B, a1B, b0B, b1B, b2B, b3B);
    MMQ(a0A, a1A, b0A, b1A, b2A, b3A);
    MMQ(a0B, a1B, b0B, b1B, b2B, b3B);
#undef MMQ

    // epilogue: bias + ReLU; lanes c16 -> 64B-contiguous segments
    #pragma unroll
    for (int i = 0; i < 2; ++i)
        #pragma unroll
        for (int r = 0; r < 4; ++r) {
            int co = co0w + i * 16 + kb * 4 + r;
            float bias = b_dcn[co];
            float* orow = out + (size_t)(b * 256 + co) * HW + posw;
            #pragma unroll
            for (int jt = 0; jt < 4; ++jt)
                orow[jt * 16 + c16] = fmaxf(acc[i][jt][r] + bias, 0.f);
        }
}

// ---------------------------------------------------------------------------
extern "C" void kernel_launch(void* const* d_in, const int* in_sizes, int n_in,
                              void* d_out, int out_size, void* d_ws, size_t ws_size,
                              hipStream_t stream) {
    const float* x     = (const float*)d_in[0];
    const float* w_om  = (const float*)d_in[1];
    const float* b_om  = (const float*)d_in[2];
    const float* w_dcn = (const float*)d_in[3];
    const float* b_dcn = (const float*)d_in[4];
    float* out = (float*)d_out;

    float* ws = (float*)d_ws;
    // offsets in float units
    float* py   = ws;                      // 147456
    float* px   = ws + 147456;
    float* msk  = ws + 294912;
    float* part = ws + 442368;             // 4*4*32*4096 = 2097152
    ushort_t* w16   = (ushort_t*)(ws + 2539520);   // 589824 f16
    ushort_t* wom16 = (ushort_t*)(ws + 2834432);   // 73728 f16
    ushort_t* xT    = (ushort_t*)(ws + 2871296);   // 4194304 f16
    ushort_t* S     = (ushort_t*)(ws + 4968448);   // up to 37748736 f16

    const size_t FULL_NEED = (size_t)(4968448 + 18874368) * 4;  // ~95.4 MB
    bool full = ws_size >= FULL_NEED;

    prep_w   <<<2592, 256, 0, stream>>>(w_dcn, w_om, w16, wom16);
    xpose    <<<2048, 256, 0, stream>>>(x, xT);
    om_gemm  <<<256,  256, 0, stream>>>(xT, wom16, part);
    om_reduce<<<1728, 256, 0, stream>>>(part, b_om, py, px, msk);

    if (full) {
        dcn_sample<<<576, 256, 0, stream>>>(x, py, px, msk, S, 0);
        dcn_gemm  <<<512, 256, 0, stream>>>(w16, S, b_dcn, out, 0);
    } else {
        for (int b0 = 0; b0 < 4; ++b0) {
            dcn_sample<<<144, 256, 0, stream>>>(x, py, px, msk, S, b0);
            dcn_gemm  <<<128, 256, 0, stream>>>(w16, S, b_dcn, out, b0);
        }
    }
}

// Round 4
// 110.657 us; speedup vs baseline: 8.0112x; 1.6372x over previous
//
#include <hip/hip_runtime.h>
#include <math.h>

typedef _Float16 f16x8 __attribute__((ext_vector_type(8)));
typedef float f32x4 __attribute__((ext_vector_type(4)));
typedef unsigned short ushort_t;

#define HW 4096

__device__ __forceinline__ ushort_t f2h_u(float v) {
    union { _Float16 h; ushort_t u; } cv; cv.h = (_Float16)v; return cv.u;
}

#define MFMA16 __builtin_amdgcn_mfma_f32_16x16x32_f16

// ---------------------------------------------------------------------------
// prep_w: f16 weight layouts.
//   w16  [9][8][256co][32kk] = w_dcn[co][c8*32+kk][k]
//   wom16[9][8][32m ][32kk]  = w_om [m ][c8*32+kk][k]  (m>=27 -> 0)
// ---------------------------------------------------------------------------
__global__ __launch_bounds__(256) void prep_w(
    const float* __restrict__ w_dcn, const float* __restrict__ w_om,
    ushort_t* __restrict__ w16, ushort_t* __restrict__ wom16)
{
    int flat = blockIdx.x * 256 + threadIdx.x;   // 589824 + 73728
    if (flat < 589824) {
        int kk = flat & 31, co = (flat >> 5) & 255, c8 = (flat >> 13) & 7, k = flat >> 16;
        w16[flat] = f2h_u(w_dcn[(size_t)(co * 256 + c8 * 32 + kk) * 9 + k]);
    } else {
        int o = flat - 589824;
        int kk = o & 31, m = (o >> 5) & 31, c8 = (o >> 10) & 7, k = o >> 13;
        float v = (m < 27) ? w_om[(size_t)(m * 256 + c8 * 32 + kk) * 9 + k] : 0.0f;
        wom16[o] = f2h_u(v);
    }
}

// ---------------------------------------------------------------------------
// xpose: x f32 [b][ci][pos] -> xT f16 [b][pos][ci], LDS-tiled so global reads
// are 256B-coalesced AND global writes are full-line 64B contiguous chunks.
// Block = (b, pos64). LDS tile [64pos][256ci] f16, XOR-swizzled 16B lanes.
// ---------------------------------------------------------------------------
__global__ __launch_bounds__(256) void xpose(
    const float* __restrict__ x, ushort_t* __restrict__ xT)
{
    int b    = blockIdx.x >> 6;
    int pos0 = (blockIdx.x & 63) * 64;
    int tid  = threadIdx.x;
    __shared__ ushort_t lds[64 * 256];           // 32 KB

    int posw = tid & 63;
    int ciq  = tid >> 6;                         // 0..3
    const float* xb = x + (size_t)b * 256 * HW + pos0 + posw;
    #pragma unroll
    for (int it = 0; it < 8; ++it) {
        int ci = it * 32 + ciq * 8;
        f16x8 hv;
        #pragma unroll
        for (int j = 0; j < 8; ++j)
            hv[j] = (_Float16)xb[(size_t)(ci + j) * HW];
        int off = posw * 512 + ((ci * 2) ^ ((posw & 7) << 4));
        *(f16x8*)((char*)lds + off) = hv;
    }
    __syncthreads();
    int posr = tid >> 2;                         // 0..63
    int cg   = tid & 3;
    char* dst = (char*)(xT + ((size_t)(b * HW) + pos0 + posr) * 256);
    #pragma unroll
    for (int u = 0; u < 8; ++u) {
        int cB = u * 64 + cg * 16;               // byte column
        f16x8 hv = *(const f16x8*)((const char*)lds + posr * 512 + (cB ^ ((posr & 7) << 4)));
        *(f16x8*)(dst + cB) = hv;                // 4 lanes -> one full 64B line
    }
}

// ---------------------------------------------------------------------------
// om_gemm: offset-mask conv as barrier-free MFMA GEMM. M=32(pad27), N=pos,
// K=(tap,ci). Wave = 32m x 64pos (one ho row); K-split x8 by 32-ci chunks.
// ---------------------------------------------------------------------------
__global__ __launch_bounds__(256) void om_gemm(
    const ushort_t* __restrict__ xT, const ushort_t* __restrict__ wom16,
    float* __restrict__ part)
{
    int wid = blockIdx.x * 4 + (threadIdx.x >> 6);  // 2048 waves
    int s  = wid & 7;
    int ho = (wid >> 3) & 63;
    int b  = wid >> 9;
    int l  = threadIdx.x & 63;
    int kb = l >> 4, c16 = l & 15;

    f32x4 zv = {0.f, 0.f, 0.f, 0.f};
    f32x4 acc[2][4];
    #pragma unroll
    for (int i = 0; i < 2; ++i)
        #pragma unroll
        for (int j = 0; j < 4; ++j) acc[i][j] = zv;
    f16x8 hz;
    #pragma unroll
    for (int j = 0; j < 8; ++j) hz[j] = (_Float16)0.0f;

    const ushort_t* xTb = xT + (size_t)b * HW * 256;

    for (int k9 = 0; k9 < 9; ++k9) {
        int kh = k9 / 3, kw = k9 - kh * 3;
        int y = ho - 1 + kh;
        bool yv = (y >= 0) & (y < 64);
        int yc = min(max(y, 0), 63);
        const ushort_t* wp = wom16 + ((size_t)((k9 * 8 + s) * 32 + c16)) * 32 + kb * 8;
        f16x8 a0 = *(const f16x8*)wp;
        f16x8 a1 = *(const f16x8*)(wp + 512);
        f16x8 bf[4];
        #pragma unroll
        for (int jt = 0; jt < 4; ++jt) {
            int wo = jt * 16 + c16;
            int wox = wo + kw - 1;
            bool v = yv & (wox >= 0) & (wox < 64);
            int woc = min(max(wox, 0), 63);
            const ushort_t* sp = xTb + ((size_t)(yc * 64 + woc)) * 256 + s * 32 + kb * 8;
            f16x8 bv = *(const f16x8*)sp;
            bf[jt] = v ? bv : hz;
        }
        #pragma unroll
        for (int jt = 0; jt < 4; ++jt) {
            acc[0][jt] = MFMA16(a0, bf[jt], acc[0][jt], 0, 0, 0);
            acc[1][jt] = MFMA16(a1, bf[jt], acc[1][jt], 0, 0, 0);
        }
    }
    int pos0 = ho * 64;
    #pragma unroll
    for (int i = 0; i < 2; ++i)
        #pragma unroll
        for (int jt = 0; jt < 4; ++jt)
            #pragma unroll
            for (int r = 0; r < 4; ++r) {
                int m = i * 16 + kb * 4 + r;
                part[((size_t)(b * 8 + s) * 32 + m) * HW + pos0 + jt * 16 + c16] = acc[i][jt][r];
            }
}

// ---------------------------------------------------------------------------
// om_reduce: sum 8 K-partials + bias -> py/px/sigmoid(mask).
// ---------------------------------------------------------------------------
__global__ __launch_bounds__(256) void om_reduce(
    const float* __restrict__ part, const float* __restrict__ b_om,
    float* __restrict__ py, float* __restrict__ px, float* __restrict__ msk)
{
    int flat = blockIdx.x * 256 + threadIdx.x;   // 4*27*4096
    int pos = flat & 4095;
    int t = flat >> 12;
    int ch = t % 27;
    int b = t / 27;
    float val = b_om[ch];
    #pragma unroll
    for (int pr = 0; pr < 8; ++pr)
        val += part[((size_t)(b * 8 + pr) * 32 + ch) * HW + pos];
    int ho = pos >> 6, wo = pos & 63;
    if (ch < 9) {
        int kh = ch / 3;
        py[(size_t)(b * 9 + ch) * HW + pos] = (float)(ho - 1 + kh) + val;
    } else if (ch < 18) {
        int k = ch - 9, kw = k % 3;
        px[(size_t)(b * 9 + k) * HW + pos] = (float)(wo - 1 + kw) + val;
    } else {
        int k = ch - 18;
        msk[(size_t)(b * 9 + k) * HW + pos] = 1.0f / (1.0f + expf(-val));
    }
}

// ---------------------------------------------------------------------------
// dcn_sample: masked bilinear im2col from xT (f16, [pos][ci]) -> S.
// One corner x 8ci = ONE 16B 64B-aligned load (vs 8 strided f32 gathers).
// Thread = (brel,k, g8, pos): 32 ci each -> 8x parallelism vs R3.
// S layout [(t*32+g)][pos][8ci]; stores 1KB-contiguous per wave.
// ---------------------------------------------------------------------------
__global__ __launch_bounds__(256) void dcn_sample(
    const ushort_t* __restrict__ xT, const float* __restrict__ py,
    const float* __restrict__ px, const float* __restrict__ msk,
    ushort_t* __restrict__ S, int b0)
{
    int flat = blockIdx.x * 256 + threadIdx.x;   // nb*9*8*4096
    int pos = flat & 4095;
    int g8  = (flat >> 12) & 7;
    int t   = flat >> 15;                        // brel*9 + k
    int brel = t / 9;
    int k = t - brel * 9;
    int b = b0 + brel;
    size_t gidx = (size_t)(b * 9 + k) * HW + pos;
    float fy = py[gidx], fx = px[gidx], mv = msk[gidx];
    float y0f = floorf(fy), x0f = floorf(fx);
    int y0 = (int)y0f, x0 = (int)x0f;
    float dy = fy - y0f, dx = fx - x0f;
    bool vy0 = (y0 >= 0) & (y0 < 64);
    bool vy1 = (y0 >= -1) & (y0 < 63);
    bool vx0 = (x0 >= 0) & (x0 < 64);
    bool vx1 = (x0 >= -1) & (x0 < 63);
    int y0c = min(max(y0, 0), 63), y1c = min(max(y0 + 1, 0), 63);
    int x0c = min(max(x0, 0), 63), x1c = min(max(x0 + 1, 0), 63);
    float w00 = (vy0 && vx0) ? (1.f - dy) * (1.f - dx) * mv : 0.f;
    float w01 = (vy0 && vx1) ? (1.f - dy) * dx * mv : 0.f;
    float w10 = (vy1 && vx0) ? dy * (1.f - dx) * mv : 0.f;
    float w11 = (vy1 && vx1) ? dy * dx * mv : 0.f;

    const ushort_t* xTb = xT + ((size_t)b * HW) * 256 + g8 * 32;
    const ushort_t* p00 = xTb + (size_t)(y0c * 64 + x0c) * 256;
    const ushort_t* p01 = xTb + (size_t)(y0c * 64 + x1c) * 256;
    const ushort_t* p10 = xTb + (size_t)(y1c * 64 + x0c) * 256;
    const ushort_t* p11 = xTb + (size_t)(y1c * 64 + x1c) * 256;
    ushort_t* Sp = S + ((size_t)(t * 32 + g8 * 4) * HW + pos) * 8;

    #pragma unroll
    for (int q = 0; q < 4; ++q) {
        f16x8 c00 = *(const f16x8*)(p00 + q * 8);
        f16x8 c01 = *(const f16x8*)(p01 + q * 8);
        f16x8 c10 = *(const f16x8*)(p10 + q * 8);
        f16x8 c11 = *(const f16x8*)(p11 + q * 8);
        f16x8 hv;
        #pragma unroll
        for (int j = 0; j < 8; ++j) {
            float v = (float)c00[j] * w00 + (float)c01[j] * w01
                    + (float)c10[j] * w10 + (float)c11[j] * w11;
            hv[j] = (_Float16)v;
        }
        *(f16x8*)(Sp + (size_t)q * (HW * 8)) = hv;
    }
}

// ---------------------------------------------------------------------------
// dcn_gemm: barrier-free, LDS-free MFMA GEMM (unchanged from R3).
// ---------------------------------------------------------------------------
__device__ __forceinline__ void ld_chunk(
    const ushort_t* __restrict__ w16, const ushort_t* __restrict__ S,
    int it, int co_a, int c16, int kb, size_t sb32, int posw,
    f16x8& a0, f16x8& a1, f16x8& b0, f16x8& b1, f16x8& b2, f16x8& b3)
{
    int k9 = it >> 3, c8 = it & 7;
    const ushort_t* wp = w16 + ((size_t)((k9 * 8 + c8) * 256 + co_a)) * 32 + kb * 8;
    a0 = *(const f16x8*)wp;
    a1 = *(const f16x8*)(wp + 512);
    const ushort_t* sp = S + ((sb32 + (size_t)(k9 * 32 + c8 * 4 + kb)) * HW + posw + c16) * 8;
    b0 = *(const f16x8*)sp;
    b1 = *(const f16x8*)(sp + 128);
    b2 = *(const f16x8*)(sp + 256);
    b3 = *(const f16x8*)(sp + 384);
}

__global__ __launch_bounds__(256) void dcn_gemm(
    const ushort_t* __restrict__ w16, const ushort_t* __restrict__ S,
    const float* __restrict__ b_dcn, float* __restrict__ out, int b0)
{
    int bid = blockIdx.x;
    int chalf = bid & 1;
    int pt = bid >> 1;
    int brel = pt >> 6;
    int b = b0 + brel;
    int posw = (pt & 63) * 64;
    int tid = threadIdx.x;
    int w = tid >> 6, l = tid & 63;
    int kb = l >> 4, c16 = l & 15;
    int co0w = chalf * 128 + w * 32;
    int co_a = co0w + c16;
    size_t sb32 = (size_t)brel * 288;

    f32x4 zv = {0.f, 0.f, 0.f, 0.f};
    f32x4 acc[2][4];
    #pragma unroll
    for (int i = 0; i < 2; ++i)
        #pragma unroll
        for (int j = 0; j < 4; ++j) acc[i][j] = zv;

    f16x8 a0A, a1A, b0A, b1A, b2A, b3A;
    f16x8 a0B, a1B, b0B, b1B, b2B, b3B;

#define MMQ(A0, A1, B0, B1, B2, B3)                          \
    do {                                                      \
        acc[0][0] = MFMA16(A0, B0, acc[0][0], 0, 0, 0);       \
        acc[1][0] = MFMA16(A1, B0, acc[1][0], 0, 0, 0);       \
        acc[0][1] = MFMA16(A0, B1, acc[0][1], 0, 0, 0);       \
        acc[1][1] = MFMA16(A1, B1, acc[1][1], 0, 0, 0);       \
        acc[0][2] = MFMA16(A0, B2, acc[0][2], 0, 0, 0);       \
        acc[1][2] = MFMA16(A1, B2, acc[1][2], 0, 0, 0);       \
        acc[0][3] = MFMA16(A0, B3, acc[0][3], 0, 0, 0);       \
        acc[1][3] = MFMA16(A1, B3, acc[1][3], 0, 0, 0);       \
    } while (0)

    ld_chunk(w16, S, 0, co_a, c16, kb, sb32, posw, a0A, a1A, b0A, b1A, b2A, b3A);
    for (int it = 0; it < 70; it += 2) {
        ld_chunk(w16, S, it + 1, co_a, c16, kb, sb32, posw, a0B, a1B, b0B, b1B, b2B, b3B);
        MMQ(a0A, a1A, b0A, b1A, b2A, b3A);
        ld_chunk(w16, S, it + 2, co_a, c16, kb, sb32, posw, a0A, a1A, b0A, b1A, b2A, b3A);
        MMQ(a0B, a1B, b0B, b1B, b2B, b3B);
    }
    ld_chunk(w16, S, 71, co_a, c16, kb, sb32, posw, a0B, a1B, b0B, b1B, b2B, b3B);
    MMQ(a0A, a1A, b0A, b1A, b2A, b3A);
    MMQ(a0B, a1B, b0B, b1B, b2B, b3B);
#undef MMQ

    #pragma unroll
    for (int i = 0; i < 2; ++i)
        #pragma unroll
        for (int r = 0; r < 4; ++r) {
            int co = co0w + i * 16 + kb * 4 + r;
            float bias = b_dcn[co];
            float* orow = out + (size_t)(b * 256 + co) * HW + posw;
            #pragma unroll
            for (int jt = 0; jt < 4; ++jt)
                orow[jt * 16 + c16] = fmaxf(acc[i][jt][r] + bias, 0.f);
        }
}

// ---------------------------------------------------------------------------
extern "C" void kernel_launch(void* const* d_in, const int* in_sizes, int n_in,
                              void* d_out, int out_size, void* d_ws, size_t ws_size,
                              hipStream_t stream) {
    const float* x     = (const float*)d_in[0];
    const float* w_om  = (const float*)d_in[1];
    const float* b_om  = (const float*)d_in[2];
    const float* w_dcn = (const float*)d_in[3];
    const float* b_dcn = (const float*)d_in[4];
    float* out = (float*)d_out;

    float* ws = (float*)d_ws;
    // float-offsets
    float* py   = ws;                              // 147456
    float* px   = ws + 147456;
    float* msk  = ws + 294912;
    ushort_t* w16   = (ushort_t*)(ws + 442368);    // 589824 f16
    ushort_t* wom16 = (ushort_t*)(ws + 737280);    // 73728 f16
    ushort_t* xT    = (ushort_t*)(ws + 774144);    // 4,194,304 f16
    float* part = ws + 2871296;                    // 4*8*32*4096 f32 (aliases S)
    ushort_t* S = (ushort_t*)(ws + 2871296);       // up to 37,748,736 f16

    const size_t FULL_NEED = (size_t)(2871296 + 18874368) * 4;   // ~87 MB
    bool full = ws_size >= FULL_NEED;

    prep_w   <<<2592, 256, 0, stream>>>(w_dcn, w_om, w16, wom16);
    xpose    <<<256,  256, 0, stream>>>(x, xT);
    om_gemm  <<<512,  256, 0, stream>>>(xT, wom16, part);
    om_reduce<<<1728, 256, 0, stream>>>(part, b_om, py, px, msk);

    if (full) {
        dcn_sample<<<4608, 256, 0, stream>>>(xT, py, px, msk, S, 0);
        dcn_gemm  <<<512,  256, 0, stream>>>(w16, S, b_dcn, out, 0);
    } else {
        for (int b0 = 0; b0 < 4; ++b0) {
            dcn_sample<<<1152, 256, 0, stream>>>(xT, py, px, msk, S, b0);
            dcn_gemm  <<<128,  256, 0, stream>>>(w16, S, b_dcn, out, b0);
        }
    }
}